// Round 1
// baseline (343.771 us; speedup 1.0000x reference)
//
#include <hip/hip_runtime.h>
#include <stdint.h>

// Problem constants: B=2, T=2048, D=1024, H=16, dh=64
#define Tq 2048
#define Dd 1024
#define Hh 16

typedef unsigned short u16;
typedef __attribute__((ext_vector_type(8))) short short8;
typedef __attribute__((ext_vector_type(4))) float f32x4;

__device__ __forceinline__ u16 f2bf(float f) {
  union { float f; unsigned u; } v; v.f = f;
  unsigned r = (v.u + 0x7fffu + ((v.u >> 16) & 1u)) >> 16;  // RNE
  return (u16)r;
}
__device__ __forceinline__ float bf2f(u16 s) {
  union { unsigned u; float f; } v; v.u = ((unsigned)s) << 16;
  return v.f;
}

__device__ __forceinline__ void load_lds16(const void* g, void* l) {
  __builtin_amdgcn_global_load_lds(
      (const __attribute__((address_space(1))) unsigned*)g,
      (__attribute__((address_space(3))) unsigned*)l, 16, 0, 0);
}

__device__ __forceinline__ f32x4 mfma16(short8 a, short8 b, f32x4 c) {
  return __builtin_amdgcn_mfma_f32_16x16x32_bf16(a, b, c, 0, 0, 0);
}

// ---------------------------------------------------------------- LayerNorm
__global__ __launch_bounds__(256) void ln_kernel(
    const float* __restrict__ x, const float* __restrict__ gamma,
    const float* __restrict__ beta, u16* __restrict__ xn) {
  int row = blockIdx.x;
  int tid = threadIdx.x;
  const float4 v = ((const float4*)(x + (size_t)row * Dd))[tid];
  float s = v.x + v.y + v.z + v.w;
  float s2 = v.x * v.x + v.y * v.y + v.z * v.z + v.w * v.w;
#pragma unroll
  for (int off = 1; off < 64; off <<= 1) {
    s += __shfl_xor(s, off);
    s2 += __shfl_xor(s2, off);
  }
  __shared__ float ps[4], ps2[4];
  int w = tid >> 6;
  if ((tid & 63) == 0) { ps[w] = s; ps2[w] = s2; }
  __syncthreads();
  s = ps[0] + ps[1] + ps[2] + ps[3];
  s2 = ps2[0] + ps2[1] + ps2[2] + ps2[3];
  float mu = s * (1.0f / Dd);
  float var = s2 * (1.0f / Dd) - mu * mu;
  float rstd = rsqrtf(var + 1e-5f);
  const float4 g = ((const float4*)gamma)[tid];
  const float4 bb = ((const float4*)beta)[tid];
  union { u16 us[4]; uint2 u2; } o;
  o.us[0] = f2bf((v.x - mu) * rstd * g.x + bb.x);
  o.us[1] = f2bf((v.y - mu) * rstd * g.y + bb.y);
  o.us[2] = f2bf((v.z - mu) * rstd * g.z + bb.z);
  o.us[3] = f2bf((v.w - mu) * rstd * g.w + bb.w);
  *(uint2*)(xn + (size_t)row * Dd + tid * 4) = o.u2;
}

// ------------------------------------------- W (K x N) -> Wt (N x K), bf16
__global__ __launch_bounds__(256) void transpose_w(
    const float* __restrict__ W, u16* __restrict__ out) {
  __shared__ float t[32][33];
  int k0 = blockIdx.x * 32, n0 = blockIdx.y * 32;
  int tx = threadIdx.x & 31, ty = threadIdx.x >> 5;
#pragma unroll
  for (int i = 0; i < 4; ++i)
    t[ty + i * 8][tx] = W[(size_t)(k0 + ty + i * 8) * Dd + n0 + tx];
  __syncthreads();
#pragma unroll
  for (int i = 0; i < 4; ++i)
    out[(size_t)(n0 + ty + i * 8) * Dd + k0 + tx] = f2bf(t[tx][ty + i * 8]);
}

// -------------------------------- mask (b,q,k) int32 -> bias_t (b,k,q) bf16
__global__ __launch_bounds__(256) void mask_kernel(
    const int* __restrict__ mask, u16* __restrict__ mb) {
  __shared__ int t[32][33];
  int b = blockIdx.z;
  int k0 = blockIdx.x * 32, q0 = blockIdx.y * 32;
  const int* mp = mask + (size_t)b * Tq * Tq;
  u16* op = mb + (size_t)b * Tq * Tq;
  int tx = threadIdx.x & 31, ty = threadIdx.x >> 5;
#pragma unroll
  for (int i = 0; i < 4; ++i)
    t[ty + i * 8][tx] = mp[(size_t)(q0 + ty + i * 8) * Tq + k0 + tx];
  __syncthreads();
#pragma unroll
  for (int i = 0; i < 4; ++i)
    op[(size_t)(k0 + ty + i * 8) * Tq + q0 + tx] =
        f2bf(t[tx][ty + i * 8] ? 0.0f : -100000.0f);
}

// ------------------- V part of qkv -> Vt[b][h][dh][T] bf16 (key-contiguous)
__global__ __launch_bounds__(256) void vt_kernel(
    const u16* __restrict__ qkv, u16* __restrict__ vt) {
  __shared__ u16 t[32][33];
  int bh = blockIdx.z;
  int b = bh >> 4, h = bh & 15;
  int t0 = blockIdx.x * 32, d0 = blockIdx.y * 32;
  int tx = threadIdx.x & 31, ty = threadIdx.x >> 5;
#pragma unroll
  for (int i = 0; i < 4; ++i)
    t[ty + i * 8][tx] =
        qkv[(size_t)(b * Tq + t0 + ty + i * 8) * 3072 + 2048 + h * 64 + d0 + tx];
  __syncthreads();
#pragma unroll
  for (int i = 0; i < 4; ++i)
    vt[((size_t)bh * 64 + d0 + ty + i * 8) * Tq + t0 + tx] = t[tx][ty + i * 8];
}

// --------------------------------------------------------- bias concat 3xD
__global__ __launch_bounds__(256) void bias3_kernel(
    const float* __restrict__ bq, const float* __restrict__ bk,
    const float* __restrict__ bv, float* __restrict__ out) {
  int i = blockIdx.x * 256 + threadIdx.x;
  float v = (i < 1024) ? bq[i] : (i < 2048) ? bk[i - 1024] : bv[i - 2048];
  out[i] = v;
}

// --------------------------------------------- GEMM: C = A * Bt^T (+ epi)
// A: MxK bf16 row-major, Bt: NxK bf16 row-major.  MODE 0: bf16 C = acc+bias
// MODE 1: fp32 C = acc + bias + resid
template <int MODE>
__global__ __launch_bounds__(256) void gemm_bt(
    const u16* __restrict__ A, const u16* __restrict__ Bt,
    const float* __restrict__ bias, const float* __restrict__ resid,
    void* __restrict__ Cout, int ldc, int K) {
  __shared__ u16 As[128 * 32];
  __shared__ u16 Bs[128 * 32];
  int tid = threadIdx.x;
  int lane = tid & 63, w = tid >> 6;
  int l16 = lane & 15, quad = lane >> 4;
  int wm = w >> 1, wn = w & 1;
  int m0 = blockIdx.y * 128, n0 = blockIdx.x * 128;
  int srow = lane >> 2, scol = (lane & 3) << 3;
  const u16* ga0 = A + (size_t)(m0 + srow) * K + scol;
  const u16* gb0 = Bt + (size_t)(n0 + srow) * K + scol;
  f32x4 acc[4][4];
#pragma unroll
  for (int i = 0; i < 4; ++i)
#pragma unroll
    for (int j = 0; j < 4; ++j) acc[i][j] = {0.f, 0.f, 0.f, 0.f};

  for (int k0 = 0; k0 < K; k0 += 32) {
    __syncthreads();
    int i = w * 2;
    load_lds16(ga0 + (size_t)(i * 16) * K + k0, (char*)As + i * 1024);
    load_lds16(gb0 + (size_t)(i * 16) * K + k0, (char*)Bs + i * 1024);
    load_lds16(ga0 + (size_t)(i * 16 + 16) * K + k0, (char*)As + i * 1024 + 1024);
    load_lds16(gb0 + (size_t)(i * 16 + 16) * K + k0, (char*)Bs + i * 1024 + 1024);
    __syncthreads();
    short8 af[4], bf[4];
#pragma unroll
    for (int mt = 0; mt < 4; ++mt)
      af[mt] = *(const short8*)&As[(wm * 64 + mt * 16 + l16) * 32 + quad * 8];
#pragma unroll
    for (int nt = 0; nt < 4; ++nt)
      bf[nt] = *(const short8*)&Bs[(wn * 64 + nt * 16 + l16) * 32 + quad * 8];
#pragma unroll
    for (int mt = 0; mt < 4; ++mt)
#pragma unroll
      for (int nt = 0; nt < 4; ++nt)
        acc[mt][nt] = mfma16(af[mt], bf[nt], acc[mt][nt]);
  }
#pragma unroll
  for (int nt = 0; nt < 4; ++nt) {
    int col = n0 + wn * 64 + nt * 16 + l16;
    float bv = bias[col];
#pragma unroll
    for (int mt = 0; mt < 4; ++mt) {
#pragma unroll
      for (int r = 0; r < 4; ++r) {
        int row = m0 + wm * 64 + mt * 16 + quad * 4 + r;
        size_t idx = (size_t)row * ldc + col;
        float vv = acc[mt][nt][r] + bv;
        if (MODE == 0)
          ((u16*)Cout)[idx] = f2bf(vv);
        else
          ((float*)Cout)[idx] = vv + resid[idx];
      }
    }
  }
}

// ----------------------------------------------------- flash attention
// Computes S^T = K*Q^T per (b,h,128-q tile); wave owns 32 q rows.
// K/Q/V fragments loaded directly from global (16B/lane); P via wave-private LDS.
__global__ __launch_bounds__(256) void attn_kernel(
    const u16* __restrict__ qkv, const u16* __restrict__ vt,
    const u16* __restrict__ mb, u16* __restrict__ ybuf) {
  __shared__ u16 Plds[4][32 * 80];  // per-wave [32 q][64 key], stride 80
  int tid = threadIdx.x;
  int lane = tid & 63, w = tid >> 6;
  int l16 = lane & 15, quad = lane >> 4;
  int qt = blockIdx.x, h = blockIdx.y, b = blockIdx.z;
  int qbase = qt * 128 + w * 32;
  const u16* Qb = qkv + (size_t)b * Tq * 3072 + h * 64;
  const u16* Kb = Qb + 1024;
  const u16* Vb = vt + ((size_t)(b * Hh + h)) * 64 * Tq;
  const u16* Mb = mb + (size_t)b * Tq * Tq;
  u16* Pw = Plds[w];

  short8 qf[2][2];
#pragma unroll
  for (int nt = 0; nt < 2; ++nt)
#pragma unroll
    for (int ks = 0; ks < 2; ++ks)
      qf[nt][ks] = *(const short8*)&Qb[(size_t)(qbase + nt * 16 + l16) * 3072 +
                                       ks * 32 + quad * 8];
  f32x4 acc[2][4];
#pragma unroll
  for (int i = 0; i < 2; ++i)
#pragma unroll
    for (int j = 0; j < 4; ++j) acc[i][j] = {0.f, 0.f, 0.f, 0.f};
  float mst[2] = {-3.0e38f, -3.0e38f};
  float lst[2] = {0.f, 0.f};

  for (int kt = 0; kt < 32; ++kt) {
    int k0 = kt * 64;
    f32x4 s[4][2];
#pragma unroll
    for (int i = 0; i < 4; ++i)
#pragma unroll
      for (int j = 0; j < 2; ++j) s[i][j] = {0.f, 0.f, 0.f, 0.f};
    // S^T = K * Q^T  (rows = keys, cols = q)
#pragma unroll
    for (int mt = 0; mt < 4; ++mt)
#pragma unroll
      for (int ks = 0; ks < 2; ++ks) {
        short8 kf = *(const short8*)&Kb[(size_t)(k0 + mt * 16 + l16) * 3072 +
                                        ks * 32 + quad * 8];
#pragma unroll
        for (int nt = 0; nt < 2; ++nt) s[mt][nt] = mfma16(kf, qf[nt][ks], s[mt][nt]);
      }
    // scale + additive mask bias
#pragma unroll
    for (int mt = 0; mt < 4; ++mt) {
      int key = k0 + mt * 16 + quad * 4;
#pragma unroll
      for (int nt = 0; nt < 2; ++nt) {
        int q = qbase + nt * 16 + l16;
#pragma unroll
        for (int r = 0; r < 4; ++r) {
          float bias = bf2f(Mb[(size_t)(key + r) * Tq + q]);
          s[mt][nt][r] = s[mt][nt][r] * 0.125f + bias;
        }
      }
    }
    // online softmax per q column
    float alph[2];
#pragma unroll
    for (int nt = 0; nt < 2; ++nt) {
      float mx = -3.0e38f;
#pragma unroll
      for (int mt = 0; mt < 4; ++mt)
#pragma unroll
        for (int r = 0; r < 4; ++r) mx = fmaxf(mx, s[mt][nt][r]);
      mx = fmaxf(mx, __shfl_xor(mx, 16));
      mx = fmaxf(mx, __shfl_xor(mx, 32));
      float mnew = fmaxf(mst[nt], mx);
      alph[nt] = __expf(mst[nt] - mnew);
      mst[nt] = mnew;
      float rs = 0.f;
#pragma unroll
      for (int mt = 0; mt < 4; ++mt)
#pragma unroll
        for (int r = 0; r < 4; ++r) {
          float p = __expf(s[mt][nt][r] - mnew);
          s[mt][nt][r] = p;
          rs += p;
        }
      rs += __shfl_xor(rs, 16);
      rs += __shfl_xor(rs, 32);
      lst[nt] = lst[nt] * alph[nt] + rs;
    }
    // rescale accumulator rows by alpha (row q-local = mt2*16 + quad*4 + r)
#pragma unroll
    for (int mt2 = 0; mt2 < 2; ++mt2)
#pragma unroll
      for (int r = 0; r < 4; ++r) {
        float a = __shfl(alph[mt2], quad * 4 + r);
#pragma unroll
        for (int nt2 = 0; nt2 < 4; ++nt2) acc[mt2][nt2][r] *= a;
      }
    // write P (bf16) transposed into row-major [q][key]
#pragma unroll
    for (int nt = 0; nt < 2; ++nt)
#pragma unroll
      for (int mt = 0; mt < 4; ++mt) {
        union { u16 us[4]; uint2 u2; } pk;
#pragma unroll
        for (int r = 0; r < 4; ++r) pk.us[r] = f2bf(s[mt][nt][r]);
        *(uint2*)&Pw[(nt * 16 + l16) * 80 + mt * 16 + quad * 4] = pk.u2;
      }
    // y += P * V
    short8 pf[2][2];
#pragma unroll
    for (int mt2 = 0; mt2 < 2; ++mt2)
#pragma unroll
      for (int ks = 0; ks < 2; ++ks)
        pf[mt2][ks] = *(const short8*)&Pw[(mt2 * 16 + l16) * 80 + ks * 32 + quad * 8];
#pragma unroll
    for (int ks = 0; ks < 2; ++ks)
#pragma unroll
      for (int nt2 = 0; nt2 < 4; ++nt2) {
        short8 vf = *(const short8*)&Vb[(size_t)(nt2 * 16 + l16) * Tq + k0 +
                                        ks * 32 + quad * 8];
#pragma unroll
        for (int mt2 = 0; mt2 < 2; ++mt2)
          acc[mt2][nt2] = mfma16(pf[mt2][ks], vf, acc[mt2][nt2]);
      }
  }
  // epilogue: normalize by l, store bf16 to ybuf[row][h*64+dh]
#pragma unroll
  for (int mt2 = 0; mt2 < 2; ++mt2)
#pragma unroll
    for (int r = 0; r < 4; ++r) {
      float li = 1.0f / __shfl(lst[mt2], quad * 4 + r);
      size_t row = (size_t)b * Tq + qbase + mt2 * 16 + quad * 4 + r;
#pragma unroll
      for (int nt2 = 0; nt2 < 4; ++nt2)
        ybuf[row * Dd + h * 64 + nt2 * 16 + l16] = f2bf(acc[mt2][nt2][r] * li);
    }
}

// ---------------------------------------------------------------- launcher
extern "C" void kernel_launch(void* const* d_in, const int* in_sizes, int n_in,
                              void* d_out, int out_size, void* d_ws, size_t ws_size,
                              hipStream_t stream) {
  (void)in_sizes; (void)n_in; (void)out_size; (void)ws_size;
  const float* x = (const float*)d_in[0];
  const int* mask = (const int*)d_in[1];
  const float* gamma = (const float*)d_in[2];
  const float* beta = (const float*)d_in[3];
  const float* Wq = (const float*)d_in[4];
  const float* bq = (const float*)d_in[5];
  const float* Wk = (const float*)d_in[6];
  const float* bk = (const float*)d_in[7];
  const float* Wv = (const float*)d_in[8];
  const float* bv = (const float*)d_in[9];
  const float* Wo = (const float*)d_in[10];
  const float* bo = (const float*)d_in[11];
  float* out = (float*)d_out;
  char* ws = (char*)d_ws;

  constexpr size_t SZ_XN = (size_t)4096 * 1024 * 2;
  constexpr size_t SZ_WTQ = (size_t)3072 * 1024 * 2;
  constexpr size_t SZ_WOT = (size_t)1024 * 1024 * 2;
  constexpr size_t SZ_B3 = 3072 * 4;
  constexpr size_t SZ_QKV = (size_t)4096 * 3072 * 2;
  constexpr size_t SZ_MB = (size_t)2 * 2048 * 2048 * 2;
  constexpr size_t SZ_VT = (size_t)2 * 16 * 64 * 2048 * 2;
  size_t off = 0;
  u16* xn = (u16*)(ws + off); off += SZ_XN;
  u16* wtqkv = (u16*)(ws + off); off += SZ_WTQ;
  u16* wot = (u16*)(ws + off); off += SZ_WOT;
  float* bias3 = (float*)(ws + off); off += SZ_B3;
  u16* qkvb = (u16*)(ws + off); off += SZ_QKV;
  u16* mbt = (u16*)(ws + off); off += SZ_MB;
  u16* vtb = (u16*)(ws + off); off += SZ_VT;
  u16* ybuf = (u16*)(ws + off);

  ln_kernel<<<dim3(4096), dim3(256), 0, stream>>>(x, gamma, beta, xn);
  transpose_w<<<dim3(32, 32), dim3(256), 0, stream>>>(Wq, wtqkv);
  transpose_w<<<dim3(32, 32), dim3(256), 0, stream>>>(Wk, wtqkv + 1024 * 1024);
  transpose_w<<<dim3(32, 32), dim3(256), 0, stream>>>(Wv, wtqkv + 2 * 1024 * 1024);
  transpose_w<<<dim3(32, 32), dim3(256), 0, stream>>>(Wo, wot);
  bias3_kernel<<<dim3(12), dim3(256), 0, stream>>>(bq, bk, bv, bias3);
  mask_kernel<<<dim3(64, 64, 2), dim3(256), 0, stream>>>(mask, mbt);
  gemm_bt<0><<<dim3(24, 32), dim3(256), 0, stream>>>(xn, wtqkv, bias3, nullptr,
                                                     qkvb, 3072, 1024);
  vt_kernel<<<dim3(64, 2, 32), dim3(256), 0, stream>>>(qkvb, vtb);
  attn_kernel<<<dim3(16, 16, 2), dim3(256), 0, stream>>>(qkvb, vtb, mbt, ybuf);
  gemm_bt<1><<<dim3(8, 32), dim3(256), 0, stream>>>(ybuf, wot, bo, x, out, 1024,
                                                    1024);
}